// Round 24
// baseline (108.155 us; speedup 1.0000x reference)
//
#include <hip/hip_runtime.h>
#include <hip/hip_bf16.h>

#define NB  4
#define NC  256
#define NC8 32
#define NHW 4096
#define LOG2E 1.4426950408889634f

typedef __attribute__((ext_vector_type(8))) short bf16x8;
typedef __attribute__((ext_vector_type(4))) float f32x4;
typedef __attribute__((ext_vector_type(16))) float f32x16;
typedef __attribute__((ext_vector_type(2))) unsigned u32x2;

__device__ __forceinline__ float ex2(float x) { return __builtin_amdgcn_exp2f(x); }

__device__ __forceinline__ unsigned short f2bf(float f) {
    union { float f; unsigned u; } v; v.f = f;
    unsigned r = v.u + 0x7fffu + ((v.u >> 16) & 1u);
    return (unsigned short)(r >> 16);
}

__device__ __forceinline__ unsigned packbf2(float lo, float hi) {
    __hip_bfloat162 h = __float22bfloat162_rn(make_float2(lo, hi));
    union { __hip_bfloat162 h; unsigned u; } cv; cv.h = h; return cv.u;
}

// ---------------- q_proj: fp32 VALU, c-split og, q ONLY (r23-proven) ---------
__global__ __launch_bounds__(512) void q_proj(
    const float* __restrict__ x,
    const float* __restrict__ qw, const float* __restrict__ qb,
    unsigned short* __restrict__ qt)
{
    const int b  = blockIdx.x >> 6;
    const int nt = blockIdx.x & 63;
    const int px = threadIdx.x & 63;
    const int og = threadIdx.x >> 6;
    const int n  = nt * 64 + px;

    __shared__ float pl[8][64][33];

    const float* ip = x + (size_t)b * NC * NHW + n;
    const int c0 = og * 32;

    float a[32];
#pragma unroll
    for (int o = 0; o < 32; ++o) a[o] = 0.f;

    for (int cl = 0; cl < 32; cl += 4) {
        const int c = c0 + cl;
        float v0 = ip[(size_t)(c+0)*NHW], v1 = ip[(size_t)(c+1)*NHW];
        float v2 = ip[(size_t)(c+2)*NHW], v3 = ip[(size_t)(c+3)*NHW];
#pragma unroll
        for (int o = 0; o < 32; ++o) {
            f32x4 w = *(const f32x4*)(qw + (size_t)o * NC + c);
            a[o] = fmaf(w[0], v0, a[o]); a[o] = fmaf(w[1], v1, a[o]);
            a[o] = fmaf(w[2], v2, a[o]); a[o] = fmaf(w[3], v3, a[o]);
        }
    }
#pragma unroll
    for (int o = 0; o < 32; ++o) pl[og][px][o] = a[o];
    __syncthreads();

    float s4[4];
#pragma unroll
    for (int j = 0; j < 4; ++j) {
        float s = 0.f;
#pragma unroll
        for (int gg = 0; gg < 8; ++gg) s += pl[gg][px][og * 4 + j];
        s4[j] = s + qb[og * 4 + j];
    }
    u32x2 pk;
    pk[0] = packbf2(s4[0] * LOG2E, s4[1] * LOG2E);   // q pre-scaled for exp2
    pk[1] = packbf2(s4[2] * LOG2E, s4[3] * LOG2E);
    *(u32x2*)(qt + ((size_t)b * NHW + n) * NC8 + og * 4) = pk;
}

// ---------------- v_proj: 64 v-rows/block (2x amortized staging) + fused k ---
// Grid 512 = 4 ygrp(64 rows) x 128(b,pt). Staging (InL packs + g reads) is the
// dominant cost; doubling rows/block halves it per unit output: g traffic
// 134->67MB, pack VALU/LDS per output halved. WsL 33.8KB + InL 16.4KB = 50.2KB
// -> 3 blocks/CU. k fused on ygrp==0 blocks (r23-proven math/layout).
__global__ __launch_bounds__(256) void v_proj(
    const float* __restrict__ g, const float* __restrict__ vw,
    const float* __restrict__ vb, const float* __restrict__ kw,
    const float* __restrict__ kb, unsigned short* __restrict__ vt,
    unsigned short* __restrict__ kt)
{
    const int id  = blockIdx.x;
    const int ygrp = id >> 7;                // 0..3: 64-row group
    const int r_  = id & 127;
    const int b   = r_ >> 5;
    const int pt  = r_ & 31;
    const int row0 = ygrp * 64;
    const int tid = threadIdx.x;
    const int wv  = tid >> 6;
    const int lane = tid & 63;
    const int l16 = lane & 15;
    const int g4  = lane >> 4;
    const int px0 = pt * 128;

    __shared__ alignas(16) unsigned short WsL[64][264];
    __shared__ alignas(16) unsigned short InL[2][128][32];

    {   // stage 64 W rows: thread t -> row t>>2, 64-c slice (t&3)*64
        const int wrow = tid >> 2;
        const int wcb  = (tid & 3) * 64;
        const float* wsrc = vw + (size_t)(row0 + wrow) * NC + wcb;
#pragma unroll
        for (int q = 0; q < 8; ++q) {
            f32x4 a  = *(const f32x4*)(wsrc + q * 8);
            f32x4 b2 = *(const f32x4*)(wsrc + q * 8 + 4);
            union { unsigned u[4]; bf16x8 v; } pk8;
            pk8.u[0] = packbf2(a[0],  a[1]);  pk8.u[1] = packbf2(a[2],  a[3]);
            pk8.u[2] = packbf2(b2[0], b2[1]); pk8.u[3] = packbf2(b2[2], b2[3]);
            *(bf16x8*)&WsL[wrow][wcb + q * 8] = pk8.v;
        }
    }

    const int spx = tid & 127;
    const int sch = (tid >> 7) * 16;
    const float* gb = g + (size_t)b * NC * NHW + px0 + spx;

    auto ldregs = [&](int c0, float pv[2][8]) {
#pragma unroll
        for (int j = 0; j < 2; ++j)
#pragma unroll
            for (int q = 0; q < 8; ++q)
                pv[j][q] = gb[(size_t)(c0 + sch + j * 8 + q) * NHW];
    };
    auto wrlds = [&](int buf, float pv[2][8]) {
#pragma unroll
        for (int j = 0; j < 2; ++j) {
            union { unsigned u[4]; bf16x8 v; } pk8;
            pk8.u[0] = packbf2(pv[j][0], pv[j][1]); pk8.u[1] = packbf2(pv[j][2], pv[j][3]);
            pk8.u[2] = packbf2(pv[j][4], pv[j][5]); pk8.u[3] = packbf2(pv[j][6], pv[j][7]);
            *(bf16x8*)&InL[buf][spx][sch + j * 8] = pk8.v;
        }
    };

    f32x4 z = {0.f, 0.f, 0.f, 0.f};
    f32x4 acc[4][2];                          // [rt: 4x16 rows][ntl]
#pragma unroll
    for (int rt = 0; rt < 4; ++rt) { acc[rt][0] = z; acc[rt][1] = z; }
    f32x4 acck[2][2] = {{z, z}, {z, z}};      // k accumulators (ygrp==0 only)

    float pv[2][8];
    ldregs(0, pv);
    wrlds(0, pv);
    __syncthreads();

    int buf = 0;
    for (int c0 = 0; c0 < NC; c0 += 32) {
        if (c0 + 32 < NC) ldregs(c0 + 32, pv);

        bf16x8 bfg0 = *(const bf16x8*)&InL[buf][(wv * 2 + 0) * 16 + l16][g4 * 8];
        bf16x8 bfg1 = *(const bf16x8*)&InL[buf][(wv * 2 + 1) * 16 + l16][g4 * 8];
#pragma unroll
        for (int rt = 0; rt < 4; ++rt) {
            bf16x8 af = *(const bf16x8*)&WsL[rt * 16 + l16][c0 + g4 * 8];
            acc[rt][0] = __builtin_amdgcn_mfma_f32_16x16x32_bf16(af, bfg0, acc[rt][0], 0, 0, 0);
            acc[rt][1] = __builtin_amdgcn_mfma_f32_16x16x32_bf16(af, bfg1, acc[rt][1], 0, 0, 0);
        }

        if (ygrp == 0) {   // fused k on the same B-frags (r23-proven)
            const float* ks0 = kw + (size_t)l16 * NC + c0 + g4 * 8;
            const float* ks1 = kw + (size_t)(16 + l16) * NC + c0 + g4 * 8;
            f32x4 a0 = *(const f32x4*)ks0, a1 = *(const f32x4*)(ks0 + 4);
            f32x4 b0 = *(const f32x4*)ks1, b1 = *(const f32x4*)(ks1 + 4);
            union { unsigned u[4]; bf16x8 v; } p0, p1;
            p0.u[0] = packbf2(a0[0], a0[1]); p0.u[1] = packbf2(a0[2], a0[3]);
            p0.u[2] = packbf2(a1[0], a1[1]); p0.u[3] = packbf2(a1[2], a1[3]);
            p1.u[0] = packbf2(b0[0], b0[1]); p1.u[1] = packbf2(b0[2], b0[3]);
            p1.u[2] = packbf2(b1[0], b1[1]); p1.u[3] = packbf2(b1[2], b1[3]);
            acck[0][0] = __builtin_amdgcn_mfma_f32_16x16x32_bf16(p0.v, bfg0, acck[0][0], 0, 0, 0);
            acck[1][0] = __builtin_amdgcn_mfma_f32_16x16x32_bf16(p1.v, bfg0, acck[1][0], 0, 0, 0);
            acck[0][1] = __builtin_amdgcn_mfma_f32_16x16x32_bf16(p0.v, bfg1, acck[0][1], 0, 0, 0);
            acck[1][1] = __builtin_amdgcn_mfma_f32_16x16x32_bf16(p1.v, bfg1, acck[1][1], 0, 0, 0);
        }

        if (c0 + 32 < NC) {
            wrlds(buf ^ 1, pv);
            __syncthreads();
            buf ^= 1;
        }
    }

#pragma unroll
    for (int rt = 0; rt < 4; ++rt) {
        f32x4 b4 = *(const f32x4*)(vb + row0 + rt * 16 + g4 * 4);
#pragma unroll
        for (int ntl = 0; ntl < 2; ++ntl) {
            const int n  = px0 + (wv * 2 + ntl) * 16 + l16;
            const int mg = n >> 3, mo = n & 7;
#pragma unroll
            for (int r = 0; r < 4; ++r) {
                const int c = row0 + rt * 16 + g4 * 4 + r;
                vt[(((size_t)b * (NHW / 8) + mg) * NC + c) * 8 + mo] =
                    f2bf(acc[rt][ntl][r] + b4[r]);
            }
        }
    }
    if (ygrp == 0) {
#pragma unroll
        for (int rt = 0; rt < 2; ++rt) {
            f32x4 kb4 = *(const f32x4*)(kb + rt * 16 + g4 * 4);
#pragma unroll
            for (int ntl = 0; ntl < 2; ++ntl) {
                const int n = px0 + (wv * 2 + ntl) * 16 + l16;
#pragma unroll
                for (int r = 0; r < 4; ++r)
                    kt[((size_t)b * NHW + n) * NC8 + rt * 16 + g4 * 4 + r] =
                        f2bf(acck[rt][ntl][r] + kb4[r]);
            }
        }
    }
}

// ---------------- attn: EXACT r17 (proven ~70.5-72us) ------------------------
__global__ __launch_bounds__(512, 2) void attn(
    const unsigned short* __restrict__ qt, const unsigned short* __restrict__ kt,
    const unsigned short* __restrict__ vt, const float* __restrict__ x,
    const float* __restrict__ gamma, float* __restrict__ out)
{
    const int b   = blockIdx.x & 3;          // XCD swizzle (r12-proven)
    const int nt  = blockIdx.x >> 2;
    const int tid = threadIdx.x;
    const int wv  = tid >> 6;                // 0..7
    const int rg  = (wv >> 2) & 1;           // row-group (32 rows)
    const int cg  = (wv >> 1) & 1;           // c-half (128 ch)
    const int s   = wv & 1;                  // key-half (2048 keys)
    const int lane = tid & 63;
    const int c32 = lane & 31;
    const int hi  = lane >> 5;

    __shared__ alignas(16) char smem[66048];
    float* obuf = (float*)smem;              // 64KB combine buffer
    float* ml   = (float*)(smem + 65536);    // [rg][s][32]

    const unsigned short* ktb = kt + (size_t)b * NHW * NC8;
    const unsigned short* vtb = vt + (size_t)b * (NHW / 8) * NC * 8;

    const int nr0 = nt * 64 + rg * 32;
    const unsigned short* qp = qt + ((size_t)b * NHW + nr0 + c32) * NC8;
    const bf16x8 qf0 = *(const bf16x8*)(qp + hi * 8);        // d 0..15
    const bf16x8 qf1 = *(const bf16x8*)(qp + 16 + hi * 8);   // d 16..31

    f32x16 acc[4];
#pragma unroll
    for (int ct = 0; ct < 4; ++ct) acc[ct] = (f32x16)0.0f;
    float lrun = 0.f;
    const f32x16 zz = (f32x16)0.0f;

    int voff[8];
#pragma unroll
    for (int kc = 0; kc < 2; ++kc)
#pragma unroll
        for (int ct = 0; ct < 4; ++ct)
            voff[kc * 4 + ct] = (((kc * 2 + hi) * NC) + cg * 128 + ct * 32 + c32) * 8;

    const size_t VSTEP = (size_t)4 * NC * 8;     // one 32-key step of vt
    const size_t KSTEP = (size_t)32 * NC8;       // one 32-key step of kt

    const unsigned short* vApt = vtb + (size_t)(s * 256) * NC * 8;   // t even
    const unsigned short* vBpt = vApt + VSTEP;                        // t odd
    const unsigned short* kApt = ktb + (size_t)(s * 2048 + c32) * NC8 + hi * 8;
    const unsigned short* kBpt = kApt + KSTEP;

    auto loadV = [&](bf16x8* v, const unsigned short* p) {
#pragma unroll
        for (int i = 0; i < 8; ++i)
            v[i] = *(const bf16x8*)(p + voff[i]);
    };
    auto loadK = [&](bf16x8& ka, bf16x8& kb2, const unsigned short* p) {
        ka  = *(const bf16x8*)p;
        kb2 = *(const bf16x8*)(p + 16);
    };
    auto qkt_pack = [&](const bf16x8& kfa, const bf16x8& kfb, unsigned* w) {
        f32x16 e = __builtin_amdgcn_mfma_f32_32x32x16_bf16(kfa, qf0, zz, 0, 0, 0);
        e = __builtin_amdgcn_mfma_f32_32x32x16_bf16(kfb, qf1, e, 0, 0, 0);
        float ladd = 0.f;
#pragma unroll
        for (int q = 0; q < 8; ++q) {
            const float pa = ex2(e[2 * q]);
            const float pb = ex2(e[2 * q + 1]);
            ladd += pa + pb;
            w[q] = packbf2(pa, pb);
        }
        lrun += ladd;
    };
    auto pv = [&](const bf16x8* v, const unsigned* w) {
#pragma unroll
        for (int kc = 0; kc < 2; ++kc) {
            const unsigned q0 = w[kc * 4 + 0];
            const unsigned q1 = w[kc * 4 + 1];
            const unsigned q2 = w[kc * 4 + 2];
            const unsigned q3 = w[kc * 4 + 3];
            const unsigned q0x = (unsigned)__shfl_xor((int)q0, 32);
            const unsigned q1x = (unsigned)__shfl_xor((int)q1, 32);
            const unsigned q2x = (unsigned)__shfl_xor((int)q2, 32);
            const unsigned q3x = (unsigned)__shfl_xor((int)q3, 32);
            union { unsigned u[4]; bf16x8 vv; } pa;
            pa.u[0] = hi ? q2x : q0;
            pa.u[1] = hi ? q3x : q1;
            pa.u[2] = hi ? q2  : q0x;
            pa.u[3] = hi ? q3  : q1x;
#pragma unroll
            for (int ct = 0; ct < 4; ++ct)
                acc[ct] = __builtin_amdgcn_mfma_f32_32x32x16_bf16(pa.vv, v[kc * 4 + ct], acc[ct], 0, 0, 0);
        }
    };

    // ---- pipeline (r17 order): V/K 2-deep, softmax two ahead ----
    bf16x8 vA[8], vB[8], kAa, kAb, kBa, kBb;
    unsigned wA[8], wB[8];

    loadV(vA, vApt); loadK(kAa, kAb, kApt);
    loadV(vB, vBpt); loadK(kBa, kBb, kBpt);
    qkt_pack(kAa, kAb, wA);                  // w(0)
    kApt += 2 * KSTEP; loadK(kAa, kAb, kApt);        // K(2)
    qkt_pack(kBa, kBb, wB);                  // w(1)
    kBpt += 2 * KSTEP; loadK(kBa, kBb, kBpt);        // K(3)

    for (int tt = 0; tt < 32; ++tt) {
        const int t = tt * 2;
        pv(vA, wA);                          // consume w(t), vA(t)
        if (t + 2 < 64) {
            qkt_pack(kAa, kAb, wA);          // produce w(t+2) from K(t+2)
            vApt += 2 * VSTEP; loadV(vA, vApt);              // V(t+2)
            if (t + 4 < 64) { kApt += 2 * KSTEP; loadK(kAa, kAb, kApt); }  // K(t+4)
        }
        pv(vB, wB);                          // consume w(t+1), vB(t+1)
        if (t + 3 < 64) {
            qkt_pack(kBa, kBb, wB);          // produce w(t+3) from K(t+3)
            vBpt += 2 * VSTEP; loadV(vB, vBpt);              // V(t+3)
            if (t + 5 < 64) { kBpt += 2 * KSTEP; loadK(kBa, kBb, kBpt); }  // K(t+5)
        }
    }

    // ---- 2-way s-combine ----
    lrun += __shfl_xor(lrun, 32);
    ml[(rg * 2 + s) * 32 + c32] = lrun;
    __syncthreads();
    const float L = ml[(rg * 2 + 0) * 32 + c32] + ml[(rg * 2 + 1) * 32 + c32];
    const float gil = gamma[0] / L;
    float il[16];
#pragma unroll
    for (int r = 0; r < 16; ++r)
        il[r] = __shfl(gil, (r & 3) + 8 * (r >> 2) + 4 * hi);

    if (s == 1) {
#pragma unroll
        for (int ct = 0; ct < 4; ++ct)
#pragma unroll
            for (int rq = 0; rq < 4; ++rq) {
                f32x4 v;
#pragma unroll
                for (int j = 0; j < 4; ++j) v[j] = acc[ct][rq * 4 + j];
                *(f32x4*)(obuf + ((((rg * 2 + cg) * 16 + ct * 4 + rq) * 64) + lane) * 4) = v;
            }
    }
    __syncthreads();
    if (s == 0) {
#pragma unroll
        for (int ct = 0; ct < 4; ++ct) {
            const int c = cg * 128 + ct * 32 + c32;
#pragma unroll
            for (int rq = 0; rq < 4; ++rq) {
                const f32x4 p = *(const f32x4*)(obuf + ((((rg * 2 + cg) * 16 + ct * 4 + rq) * 64) + lane) * 4);
                const int nglob = nt * 64 + rg * 32 + rq * 8 + hi * 4;
                const size_t o = ((size_t)b * NC + c) * NHW + nglob;
                const f32x4 xv = *(const f32x4*)(x + o);
                f32x4 res;
#pragma unroll
                for (int j = 0; j < 4; ++j) {
                    const float v = acc[ct][rq * 4 + j] + p[j];
                    res[j] = fmaf(v, il[rq * 4 + j], xv[j]);
                }
                *(f32x4*)(out + o) = res;
            }
        }
    }
}

extern "C" void kernel_launch(void* const* d_in, const int* in_sizes, int n_in,
                              void* d_out, int out_size, void* d_ws, size_t ws_size,
                              hipStream_t stream) {
    const float* x     = (const float*)d_in[0];
    const float* g     = (const float*)d_in[1];
    const float* qw    = (const float*)d_in[2];
    const float* qb    = (const float*)d_in[3];
    const float* kw    = (const float*)d_in[4];
    const float* kb    = (const float*)d_in[5];
    const float* vw    = (const float*)d_in[6];
    const float* vb    = (const float*)d_in[7];
    const float* gamma = (const float*)d_in[8];
    float* out = (float*)d_out;

    unsigned short* qt = (unsigned short*)d_ws;
    unsigned short* kt = qt + (size_t)NB * NHW * NC8;
    unsigned short* vt = kt + (size_t)NB * NHW * NC8;

    q_proj<<<NB * (NHW / 64), 512, 0, stream>>>(x, qw, qb, qt);
    v_proj<<<512, 256, 0, stream>>>(g, vw, vb, kw, kb, vt, kt);
    attn  <<<NB * (NHW / 64), 512, 0, stream>>>(qt, kt, vt, x, gamma, out);
}

// Round 25
// 102.312 us; speedup vs baseline: 1.0571x; 1.0571x over previous
//
#include <hip/hip_runtime.h>
#include <hip/hip_bf16.h>

#define NB  4
#define NC  256
#define NC8 32
#define NHW 4096
#define LOG2E 1.4426950408889634f

typedef __attribute__((ext_vector_type(8))) short bf16x8;
typedef __attribute__((ext_vector_type(4))) float f32x4;
typedef __attribute__((ext_vector_type(16))) float f32x16;
typedef __attribute__((ext_vector_type(2))) unsigned u32x2;

__device__ __forceinline__ float ex2(float x) { return __builtin_amdgcn_exp2f(x); }

__device__ __forceinline__ unsigned short f2bf(float f) {
    union { float f; unsigned u; } v; v.f = f;
    unsigned r = v.u + 0x7fffu + ((v.u >> 16) & 1u);
    return (unsigned short)(r >> 16);
}

__device__ __forceinline__ unsigned packbf2(float lo, float hi) {
    __hip_bfloat162 h = __float22bfloat162_rn(make_float2(lo, hi));
    union { __hip_bfloat162 h; unsigned u; } cv; cv.h = h; return cv.u;
}

// ---------------- v_proj + fused k (r24, proven) ------------------------------
__global__ __launch_bounds__(256) void v_proj(
    const float* __restrict__ g, const float* __restrict__ vw,
    const float* __restrict__ vb, const float* __restrict__ kw,
    const float* __restrict__ kb, unsigned short* __restrict__ vt,
    unsigned short* __restrict__ kt)
{
    const int id  = blockIdx.x;
    const int ygrp = id >> 7;                // 0..3: 64-row group
    const int r_  = id & 127;
    const int b   = r_ >> 5;
    const int pt  = r_ & 31;
    const int row0 = ygrp * 64;
    const int tid = threadIdx.x;
    const int wv  = tid >> 6;
    const int lane = tid & 63;
    const int l16 = lane & 15;
    const int g4  = lane >> 4;
    const int px0 = pt * 128;

    __shared__ alignas(16) unsigned short WsL[64][264];
    __shared__ alignas(16) unsigned short InL[2][128][32];

    {
        const int wrow = tid >> 2;
        const int wcb  = (tid & 3) * 64;
        const float* wsrc = vw + (size_t)(row0 + wrow) * NC + wcb;
#pragma unroll
        for (int q = 0; q < 8; ++q) {
            f32x4 a  = *(const f32x4*)(wsrc + q * 8);
            f32x4 b2 = *(const f32x4*)(wsrc + q * 8 + 4);
            union { unsigned u[4]; bf16x8 v; } pk8;
            pk8.u[0] = packbf2(a[0],  a[1]);  pk8.u[1] = packbf2(a[2],  a[3]);
            pk8.u[2] = packbf2(b2[0], b2[1]); pk8.u[3] = packbf2(b2[2], b2[3]);
            *(bf16x8*)&WsL[wrow][wcb + q * 8] = pk8.v;
        }
    }

    const int spx = tid & 127;
    const int sch = (tid >> 7) * 16;
    const float* gb = g + (size_t)b * NC * NHW + px0 + spx;

    auto ldregs = [&](int c0, float pv[2][8]) {
#pragma unroll
        for (int j = 0; j < 2; ++j)
#pragma unroll
            for (int q = 0; q < 8; ++q)
                pv[j][q] = gb[(size_t)(c0 + sch + j * 8 + q) * NHW];
    };
    auto wrlds = [&](int buf, float pv[2][8]) {
#pragma unroll
        for (int j = 0; j < 2; ++j) {
            union { unsigned u[4]; bf16x8 v; } pk8;
            pk8.u[0] = packbf2(pv[j][0], pv[j][1]); pk8.u[1] = packbf2(pv[j][2], pv[j][3]);
            pk8.u[2] = packbf2(pv[j][4], pv[j][5]); pk8.u[3] = packbf2(pv[j][6], pv[j][7]);
            *(bf16x8*)&InL[buf][spx][sch + j * 8] = pk8.v;
        }
    };

    f32x4 z = {0.f, 0.f, 0.f, 0.f};
    f32x4 acc[4][2];
#pragma unroll
    for (int rt = 0; rt < 4; ++rt) { acc[rt][0] = z; acc[rt][1] = z; }
    f32x4 acck[2][2] = {{z, z}, {z, z}};

    float pv[2][8];
    ldregs(0, pv);
    wrlds(0, pv);
    __syncthreads();

    int buf = 0;
    for (int c0 = 0; c0 < NC; c0 += 32) {
        if (c0 + 32 < NC) ldregs(c0 + 32, pv);

        bf16x8 bfg0 = *(const bf16x8*)&InL[buf][(wv * 2 + 0) * 16 + l16][g4 * 8];
        bf16x8 bfg1 = *(const bf16x8*)&InL[buf][(wv * 2 + 1) * 16 + l16][g4 * 8];
#pragma unroll
        for (int rt = 0; rt < 4; ++rt) {
            bf16x8 af = *(const bf16x8*)&WsL[rt * 16 + l16][c0 + g4 * 8];
            acc[rt][0] = __builtin_amdgcn_mfma_f32_16x16x32_bf16(af, bfg0, acc[rt][0], 0, 0, 0);
            acc[rt][1] = __builtin_amdgcn_mfma_f32_16x16x32_bf16(af, bfg1, acc[rt][1], 0, 0, 0);
        }

        if (ygrp == 0) {
            const float* ks0 = kw + (size_t)l16 * NC + c0 + g4 * 8;
            const float* ks1 = kw + (size_t)(16 + l16) * NC + c0 + g4 * 8;
            f32x4 a0 = *(const f32x4*)ks0, a1 = *(const f32x4*)(ks0 + 4);
            f32x4 b0 = *(const f32x4*)ks1, b1 = *(const f32x4*)(ks1 + 4);
            union { unsigned u[4]; bf16x8 v; } p0, p1;
            p0.u[0] = packbf2(a0[0], a0[1]); p0.u[1] = packbf2(a0[2], a0[3]);
            p0.u[2] = packbf2(a1[0], a1[1]); p0.u[3] = packbf2(a1[2], a1[3]);
            p1.u[0] = packbf2(b0[0], b0[1]); p1.u[1] = packbf2(b0[2], b0[3]);
            p1.u[2] = packbf2(b1[0], b1[1]); p1.u[3] = packbf2(b1[2], b1[3]);
            acck[0][0] = __builtin_amdgcn_mfma_f32_16x16x32_bf16(p0.v, bfg0, acck[0][0], 0, 0, 0);
            acck[1][0] = __builtin_amdgcn_mfma_f32_16x16x32_bf16(p1.v, bfg0, acck[1][0], 0, 0, 0);
            acck[0][1] = __builtin_amdgcn_mfma_f32_16x16x32_bf16(p0.v, bfg1, acck[0][1], 0, 0, 0);
            acck[1][1] = __builtin_amdgcn_mfma_f32_16x16x32_bf16(p1.v, bfg1, acck[1][1], 0, 0, 0);
        }

        if (c0 + 32 < NC) {
            wrlds(buf ^ 1, pv);
            __syncthreads();
            buf ^= 1;
        }
    }

#pragma unroll
    for (int rt = 0; rt < 4; ++rt) {
        f32x4 b4 = *(const f32x4*)(vb + row0 + rt * 16 + g4 * 4);
#pragma unroll
        for (int ntl = 0; ntl < 2; ++ntl) {
            const int n  = px0 + (wv * 2 + ntl) * 16 + l16;
            const int mg = n >> 3, mo = n & 7;
#pragma unroll
            for (int r = 0; r < 4; ++r) {
                const int c = row0 + rt * 16 + g4 * 4 + r;
                vt[(((size_t)b * (NHW / 8) + mg) * NC + c) * 8 + mo] =
                    f2bf(acc[rt][ntl][r] + b4[r]);
            }
        }
    }
    if (ygrp == 0) {
#pragma unroll
        for (int rt = 0; rt < 2; ++rt) {
            f32x4 kb4 = *(const f32x4*)(kb + rt * 16 + g4 * 4);
#pragma unroll
            for (int ntl = 0; ntl < 2; ++ntl) {
                const int n = px0 + (wv * 2 + ntl) * 16 + l16;
#pragma unroll
                for (int r = 0; r < 4; ++r)
                    kt[((size_t)b * NHW + n) * NC8 + rt * 16 + g4 * 4 + r] =
                        f2bf(acck[rt][ntl][r] + kb4[r]);
            }
        }
    }
}

// ---------------- attn: r17 structure + FUSED q prologue ---------------------
// q_proj kernel eliminated: each block computes q = qw@x + qb (fp32, same math
// and rounding point as the old q_proj) for its own 64 pixels in a ~1k-FMA
// prologue. pl combine buffer (67.6KB) ALIASES the epilogue obuf (prologue-
// dead vs epilogue-dead regions); packed q lives in a separate 4KB qlds.
__global__ __launch_bounds__(512, 2) void attn(
    const float* __restrict__ x,
    const float* __restrict__ qw, const float* __restrict__ qb,
    const unsigned short* __restrict__ kt, const unsigned short* __restrict__ vt,
    const float* __restrict__ gamma, float* __restrict__ out)
{
    const int b   = blockIdx.x & 3;          // XCD swizzle (r12-proven)
    const int nt  = blockIdx.x >> 2;
    const int tid = threadIdx.x;
    const int wv  = tid >> 6;                // 0..7
    const int rg  = (wv >> 2) & 1;           // row-group (32 rows)
    const int cg  = (wv >> 1) & 1;           // c-half (128 ch)
    const int s   = wv & 1;                  // key-half (2048 keys)
    const int lane = tid & 63;
    const int c32 = lane & 31;
    const int hi  = lane >> 5;

    __shared__ alignas(16) char smem[67584];              // pl | obuf+ml (aliased)
    __shared__ alignas(16) unsigned short qlds[64][32];   // packed q (4KB)
    float* pl   = (float*)smem;              // [8][64][33] prologue combine
    float* obuf = (float*)smem;              // 64KB epilogue combine
    float* ml   = (float*)(smem + 65536);    // [rg][s][32]

    // ---- prologue: q = qw@x + qb for this block's 64 pixels (fp32) ----
    {
        const int px = tid & 63;
        const int og = tid >> 6;             // c-slice og*32..+32
        const float* ip = x + (size_t)b * NC * NHW + nt * 64 + px;
        const int c0 = og * 32;

        float a[32];
#pragma unroll
        for (int o = 0; o < 32; ++o) a[o] = 0.f;
        for (int cl = 0; cl < 32; cl += 4) {
            const int c = c0 + cl;
            float v0 = ip[(size_t)(c+0)*NHW], v1 = ip[(size_t)(c+1)*NHW];
            float v2 = ip[(size_t)(c+2)*NHW], v3 = ip[(size_t)(c+3)*NHW];
#pragma unroll
            for (int o = 0; o < 32; ++o) {
                f32x4 w = *(const f32x4*)(qw + (size_t)o * NC + c);
                a[o] = fmaf(w[0], v0, a[o]); a[o] = fmaf(w[1], v1, a[o]);
                a[o] = fmaf(w[2], v2, a[o]); a[o] = fmaf(w[3], v3, a[o]);
            }
        }
#pragma unroll
        for (int o = 0; o < 32; ++o) pl[(og * 64 + px) * 33 + o] = a[o];
        __syncthreads();

        float s4[4];
#pragma unroll
        for (int j = 0; j < 4; ++j) {
            float sum = 0.f;
#pragma unroll
            for (int gg = 0; gg < 8; ++gg) sum += pl[(gg * 64 + px) * 33 + og * 4 + j];
            s4[j] = sum + qb[og * 4 + j];
        }
        u32x2 pk;
        pk[0] = packbf2(s4[0] * LOG2E, s4[1] * LOG2E);
        pk[1] = packbf2(s4[2] * LOG2E, s4[3] * LOG2E);
        *(u32x2*)&qlds[px][og * 4] = pk;
        __syncthreads();                     // qlds ready; pl dead hereafter
    }

    const unsigned short* ktb = kt + (size_t)b * NHW * NC8;
    const unsigned short* vtb = vt + (size_t)b * (NHW / 8) * NC * 8;

    const int nr0 = nt * 64 + rg * 32;
    const bf16x8 qf0 = *(const bf16x8*)&qlds[rg * 32 + c32][hi * 8];        // d 0..15
    const bf16x8 qf1 = *(const bf16x8*)&qlds[rg * 32 + c32][16 + hi * 8];   // d 16..31

    f32x16 acc[4];
#pragma unroll
    for (int ct = 0; ct < 4; ++ct) acc[ct] = (f32x16)0.0f;
    float lrun = 0.f;
    const f32x16 zz = (f32x16)0.0f;

    int voff[8];
#pragma unroll
    for (int kc = 0; kc < 2; ++kc)
#pragma unroll
        for (int ct = 0; ct < 4; ++ct)
            voff[kc * 4 + ct] = (((kc * 2 + hi) * NC) + cg * 128 + ct * 32 + c32) * 8;

    const size_t VSTEP = (size_t)4 * NC * 8;     // one 32-key step of vt
    const size_t KSTEP = (size_t)32 * NC8;       // one 32-key step of kt

    const unsigned short* vApt = vtb + (size_t)(s * 256) * NC * 8;   // t even
    const unsigned short* vBpt = vApt + VSTEP;                        // t odd
    const unsigned short* kApt = ktb + (size_t)(s * 2048 + c32) * NC8 + hi * 8;
    const unsigned short* kBpt = kApt + KSTEP;

    auto loadV = [&](bf16x8* v, const unsigned short* p) {
#pragma unroll
        for (int i = 0; i < 8; ++i)
            v[i] = *(const bf16x8*)(p + voff[i]);
    };
    auto loadK = [&](bf16x8& ka, bf16x8& kb2, const unsigned short* p) {
        ka  = *(const bf16x8*)p;
        kb2 = *(const bf16x8*)(p + 16);
    };
    auto qkt_pack = [&](const bf16x8& kfa, const bf16x8& kfb, unsigned* w) {
        f32x16 e = __builtin_amdgcn_mfma_f32_32x32x16_bf16(kfa, qf0, zz, 0, 0, 0);
        e = __builtin_amdgcn_mfma_f32_32x32x16_bf16(kfb, qf1, e, 0, 0, 0);
        float ladd = 0.f;
#pragma unroll
        for (int q = 0; q < 8; ++q) {
            const float pa = ex2(e[2 * q]);
            const float pb = ex2(e[2 * q + 1]);
            ladd += pa + pb;
            w[q] = packbf2(pa, pb);
        }
        lrun += ladd;
    };
    auto pv = [&](const bf16x8* v, const unsigned* w) {
#pragma unroll
        for (int kc = 0; kc < 2; ++kc) {
            const unsigned q0 = w[kc * 4 + 0];
            const unsigned q1 = w[kc * 4 + 1];
            const unsigned q2 = w[kc * 4 + 2];
            const unsigned q3 = w[kc * 4 + 3];
            const unsigned q0x = (unsigned)__shfl_xor((int)q0, 32);
            const unsigned q1x = (unsigned)__shfl_xor((int)q1, 32);
            const unsigned q2x = (unsigned)__shfl_xor((int)q2, 32);
            const unsigned q3x = (unsigned)__shfl_xor((int)q3, 32);
            union { unsigned u[4]; bf16x8 vv; } pa;
            pa.u[0] = hi ? q2x : q0;
            pa.u[1] = hi ? q3x : q1;
            pa.u[2] = hi ? q2  : q0x;
            pa.u[3] = hi ? q3  : q1x;
#pragma unroll
            for (int ct = 0; ct < 4; ++ct)
                acc[ct] = __builtin_amdgcn_mfma_f32_32x32x16_bf16(pa.vv, v[kc * 4 + ct], acc[ct], 0, 0, 0);
        }
    };

    // ---- pipeline (r17 order): V/K 2-deep, softmax two ahead ----
    bf16x8 vA[8], vB[8], kAa, kAb, kBa, kBb;
    unsigned wA[8], wB[8];

    loadV(vA, vApt); loadK(kAa, kAb, kApt);
    loadV(vB, vBpt); loadK(kBa, kBb, kBpt);
    qkt_pack(kAa, kAb, wA);                  // w(0)
    kApt += 2 * KSTEP; loadK(kAa, kAb, kApt);        // K(2)
    qkt_pack(kBa, kBb, wB);                  // w(1)
    kBpt += 2 * KSTEP; loadK(kBa, kBb, kBpt);        // K(3)

    for (int tt = 0; tt < 32; ++tt) {
        const int t = tt * 2;
        pv(vA, wA);                          // consume w(t), vA(t)
        if (t + 2 < 64) {
            qkt_pack(kAa, kAb, wA);          // produce w(t+2) from K(t+2)
            vApt += 2 * VSTEP; loadV(vA, vApt);              // V(t+2)
            if (t + 4 < 64) { kApt += 2 * KSTEP; loadK(kAa, kAb, kApt); }  // K(t+4)
        }
        pv(vB, wB);                          // consume w(t+1), vB(t+1)
        if (t + 3 < 64) {
            qkt_pack(kBa, kBb, wB);          // produce w(t+3) from K(t+3)
            vBpt += 2 * VSTEP; loadV(vB, vBpt);              // V(t+3)
            if (t + 5 < 64) { kBpt += 2 * KSTEP; loadK(kBa, kBb, kBpt); }  // K(t+5)
        }
    }

    // ---- 2-way s-combine ----
    lrun += __shfl_xor(lrun, 32);
    __syncthreads();                          // all waves past prologue-pl use
    ml[(rg * 2 + s) * 32 + c32] = lrun;
    __syncthreads();
    const float L = ml[(rg * 2 + 0) * 32 + c32] + ml[(rg * 2 + 1) * 32 + c32];
    const float gil = gamma[0] / L;
    float il[16];
#pragma unroll
    for (int r = 0; r < 16; ++r)
        il[r] = __shfl(gil, (r & 3) + 8 * (r >> 2) + 4 * hi);

    if (s == 1) {
#pragma unroll
        for (int ct = 0; ct < 4; ++ct)
#pragma unroll
            for (int rq = 0; rq < 4; ++rq) {
                f32x4 v;
#pragma unroll
                for (int j = 0; j < 4; ++j) v[j] = acc[ct][rq * 4 + j];
                *(f32x4*)(obuf + ((((rg * 2 + cg) * 16 + ct * 4 + rq) * 64) + lane) * 4) = v;
            }
    }
    __syncthreads();
    if (s == 0) {
#pragma unroll
        for (int ct = 0; ct < 4; ++ct) {
            const int c = cg * 128 + ct * 32 + c32;
#pragma unroll
            for (int rq = 0; rq < 4; ++rq) {
                const f32x4 p = *(const f32x4*)(obuf + ((((rg * 2 + cg) * 16 + ct * 4 + rq) * 64) + lane) * 4);
                const int nglob = nt * 64 + rg * 32 + rq * 8 + hi * 4;
                const size_t o = ((size_t)b * NC + c) * NHW + nglob;
                const f32x4 xv = *(const f32x4*)(x + o);
                f32x4 res;
#pragma unroll
                for (int j = 0; j < 4; ++j) {
                    const float v = acc[ct][rq * 4 + j] + p[j];
                    res[j] = fmaf(v, il[rq * 4 + j], xv[j]);
                }
                *(f32x4*)(out + o) = res;
            }
        }
    }
}

extern "C" void kernel_launch(void* const* d_in, const int* in_sizes, int n_in,
                              void* d_out, int out_size, void* d_ws, size_t ws_size,
                              hipStream_t stream) {
    const float* x     = (const float*)d_in[0];
    const float* g     = (const float*)d_in[1];
    const float* qw    = (const float*)d_in[2];
    const float* qb    = (const float*)d_in[3];
    const float* kw    = (const float*)d_in[4];
    const float* kb    = (const float*)d_in[5];
    const float* vw    = (const float*)d_in[6];
    const float* vb    = (const float*)d_in[7];
    const float* gamma = (const float*)d_in[8];
    float* out = (float*)d_out;

    unsigned short* kt = (unsigned short*)d_ws;
    unsigned short* vt = kt + (size_t)NB * NHW * NC8;

    v_proj<<<512, 256, 0, stream>>>(g, vw, vb, kw, kb, vt, kt);
    attn  <<<NB * (NHW / 64), 512, 0, stream>>>(x, qw, qb, kt, vt, gamma, out);
}

// Round 26
// 93.023 us; speedup vs baseline: 1.1627x; 1.0999x over previous
//
#include <hip/hip_runtime.h>
#include <hip/hip_bf16.h>

#define NB  4
#define NC  256
#define NC8 32
#define NHW 4096
#define LOG2E 1.4426950408889634f

typedef __attribute__((ext_vector_type(8))) short bf16x8;
typedef __attribute__((ext_vector_type(4))) float f32x4;
typedef __attribute__((ext_vector_type(16))) float f32x16;
typedef __attribute__((ext_vector_type(2))) unsigned u32x2;

__device__ __forceinline__ float ex2(float x) { return __builtin_amdgcn_exp2f(x); }

__device__ __forceinline__ unsigned short f2bf(float f) {
    union { float f; unsigned u; } v; v.f = f;
    unsigned r = v.u + 0x7fffu + ((v.u >> 16) & 1u);
    return (unsigned short)(r >> 16);
}

__device__ __forceinline__ unsigned packbf2(float lo, float hi) {
    __hip_bfloat162 h = __float22bfloat162_rn(make_float2(lo, hi));
    union { __hip_bfloat162 h; unsigned u; } cv; cv.h = h; return cv.u;
}

// ---------------- v_proj + fused k (r24, proven) ------------------------------
__global__ __launch_bounds__(256) void v_proj(
    const float* __restrict__ g, const float* __restrict__ vw,
    const float* __restrict__ vb, const float* __restrict__ kw,
    const float* __restrict__ kb, unsigned short* __restrict__ vt,
    unsigned short* __restrict__ kt)
{
    const int id  = blockIdx.x;
    const int ygrp = id >> 7;                // 0..3: 64-row group
    const int r_  = id & 127;
    const int b   = r_ >> 5;
    const int pt  = r_ & 31;
    const int row0 = ygrp * 64;
    const int tid = threadIdx.x;
    const int wv  = tid >> 6;
    const int lane = tid & 63;
    const int l16 = lane & 15;
    const int g4  = lane >> 4;
    const int px0 = pt * 128;

    __shared__ alignas(16) unsigned short WsL[64][264];
    __shared__ alignas(16) unsigned short InL[2][128][32];

    {
        const int wrow = tid >> 2;
        const int wcb  = (tid & 3) * 64;
        const float* wsrc = vw + (size_t)(row0 + wrow) * NC + wcb;
#pragma unroll
        for (int q = 0; q < 8; ++q) {
            f32x4 a  = *(const f32x4*)(wsrc + q * 8);
            f32x4 b2 = *(const f32x4*)(wsrc + q * 8 + 4);
            union { unsigned u[4]; bf16x8 v; } pk8;
            pk8.u[0] = packbf2(a[0],  a[1]);  pk8.u[1] = packbf2(a[2],  a[3]);
            pk8.u[2] = packbf2(b2[0], b2[1]); pk8.u[3] = packbf2(b2[2], b2[3]);
            *(bf16x8*)&WsL[wrow][wcb + q * 8] = pk8.v;
        }
    }

    const int spx = tid & 127;
    const int sch = (tid >> 7) * 16;
    const float* gb = g + (size_t)b * NC * NHW + px0 + spx;

    auto ldregs = [&](int c0, float pv[2][8]) {
#pragma unroll
        for (int j = 0; j < 2; ++j)
#pragma unroll
            for (int q = 0; q < 8; ++q)
                pv[j][q] = gb[(size_t)(c0 + sch + j * 8 + q) * NHW];
    };
    auto wrlds = [&](int buf, float pv[2][8]) {
#pragma unroll
        for (int j = 0; j < 2; ++j) {
            union { unsigned u[4]; bf16x8 v; } pk8;
            pk8.u[0] = packbf2(pv[j][0], pv[j][1]); pk8.u[1] = packbf2(pv[j][2], pv[j][3]);
            pk8.u[2] = packbf2(pv[j][4], pv[j][5]); pk8.u[3] = packbf2(pv[j][6], pv[j][7]);
            *(bf16x8*)&InL[buf][spx][sch + j * 8] = pk8.v;
        }
    };

    f32x4 z = {0.f, 0.f, 0.f, 0.f};
    f32x4 acc[4][2];
#pragma unroll
    for (int rt = 0; rt < 4; ++rt) { acc[rt][0] = z; acc[rt][1] = z; }
    f32x4 acck[2][2] = {{z, z}, {z, z}};

    float pv[2][8];
    ldregs(0, pv);
    wrlds(0, pv);
    __syncthreads();

    int buf = 0;
    for (int c0 = 0; c0 < NC; c0 += 32) {
        if (c0 + 32 < NC) ldregs(c0 + 32, pv);

        bf16x8 bfg0 = *(const bf16x8*)&InL[buf][(wv * 2 + 0) * 16 + l16][g4 * 8];
        bf16x8 bfg1 = *(const bf16x8*)&InL[buf][(wv * 2 + 1) * 16 + l16][g4 * 8];
#pragma unroll
        for (int rt = 0; rt < 4; ++rt) {
            bf16x8 af = *(const bf16x8*)&WsL[rt * 16 + l16][c0 + g4 * 8];
            acc[rt][0] = __builtin_amdgcn_mfma_f32_16x16x32_bf16(af, bfg0, acc[rt][0], 0, 0, 0);
            acc[rt][1] = __builtin_amdgcn_mfma_f32_16x16x32_bf16(af, bfg1, acc[rt][1], 0, 0, 0);
        }

        if (ygrp == 0) {
            const float* ks0 = kw + (size_t)l16 * NC + c0 + g4 * 8;
            const float* ks1 = kw + (size_t)(16 + l16) * NC + c0 + g4 * 8;
            f32x4 a0 = *(const f32x4*)ks0, a1 = *(const f32x4*)(ks0 + 4);
            f32x4 b0 = *(const f32x4*)ks1, b1 = *(const f32x4*)(ks1 + 4);
            union { unsigned u[4]; bf16x8 v; } p0, p1;
            p0.u[0] = packbf2(a0[0], a0[1]); p0.u[1] = packbf2(a0[2], a0[3]);
            p0.u[2] = packbf2(a1[0], a1[1]); p0.u[3] = packbf2(a1[2], a1[3]);
            p1.u[0] = packbf2(b0[0], b0[1]); p1.u[1] = packbf2(b0[2], b0[3]);
            p1.u[2] = packbf2(b1[0], b1[1]); p1.u[3] = packbf2(b1[2], b1[3]);
            acck[0][0] = __builtin_amdgcn_mfma_f32_16x16x32_bf16(p0.v, bfg0, acck[0][0], 0, 0, 0);
            acck[1][0] = __builtin_amdgcn_mfma_f32_16x16x32_bf16(p1.v, bfg0, acck[1][0], 0, 0, 0);
            acck[0][1] = __builtin_amdgcn_mfma_f32_16x16x32_bf16(p0.v, bfg1, acck[0][1], 0, 0, 0);
            acck[1][1] = __builtin_amdgcn_mfma_f32_16x16x32_bf16(p1.v, bfg1, acck[1][1], 0, 0, 0);
        }

        if (c0 + 32 < NC) {
            wrlds(buf ^ 1, pv);
            __syncthreads();
            buf ^= 1;
        }
    }

#pragma unroll
    for (int rt = 0; rt < 4; ++rt) {
        f32x4 b4 = *(const f32x4*)(vb + row0 + rt * 16 + g4 * 4);
#pragma unroll
        for (int ntl = 0; ntl < 2; ++ntl) {
            const int n  = px0 + (wv * 2 + ntl) * 16 + l16;
            const int mg = n >> 3, mo = n & 7;
#pragma unroll
            for (int r = 0; r < 4; ++r) {
                const int c = row0 + rt * 16 + g4 * 4 + r;
                vt[(((size_t)b * (NHW / 8) + mg) * NC + c) * 8 + mo] =
                    f2bf(acc[rt][ntl][r] + b4[r]);
            }
        }
    }
    if (ygrp == 0) {
#pragma unroll
        for (int rt = 0; rt < 2; ++rt) {
            f32x4 kb4 = *(const f32x4*)(kb + rt * 16 + g4 * 4);
#pragma unroll
            for (int ntl = 0; ntl < 2; ++ntl) {
                const int n = px0 + (wv * 2 + ntl) * 16 + l16;
#pragma unroll
                for (int r = 0; r < 4; ++r)
                    kt[((size_t)b * NHW + n) * NC8 + rt * 16 + g4 * 4 + r] =
                        f2bf(acck[rt][ntl][r] + kb4[r]);
            }
        }
    }
}

// ---------------- attn: r25 + qw staged in LDS for the q prologue ------------
// r25's prologue spent ~20us on 256 global f32x4 qw loads per thread. Fix:
// stage qw (32KB) into LDS once per block (4 coalesced loads/thread); the
// accumulate loop then reads qw via wave-uniform LDS broadcast. qwL ALIASES
// the pl region (qwL dead before pl is written; barrier separates them), so
// block LDS stays 71.7KB -> 2 blocks/CU unchanged.
__global__ __launch_bounds__(512, 2) void attn(
    const float* __restrict__ x,
    const float* __restrict__ qw, const float* __restrict__ qb,
    const unsigned short* __restrict__ kt, const unsigned short* __restrict__ vt,
    const float* __restrict__ gamma, float* __restrict__ out)
{
    const int b   = blockIdx.x & 3;          // XCD swizzle (r12-proven)
    const int nt  = blockIdx.x >> 2;
    const int tid = threadIdx.x;
    const int wv  = tid >> 6;                // 0..7
    const int rg  = (wv >> 2) & 1;           // row-group (32 rows)
    const int cg  = (wv >> 1) & 1;           // c-half (128 ch)
    const int s   = wv & 1;                  // key-half (2048 keys)
    const int lane = tid & 63;
    const int c32 = lane & 31;
    const int hi  = lane >> 5;

    __shared__ alignas(16) char smem[67584];              // qwL | pl | obuf+ml (aliased)
    __shared__ alignas(16) unsigned short qlds[64][32];   // packed q (4KB)
    float* qwL  = (float*)smem;              // 32KB staged qw (prologue phase 1)
    float* pl   = (float*)smem;              // [8][64][33] prologue combine (phase 2)
    float* obuf = (float*)smem;              // 64KB epilogue combine
    float* ml   = (float*)(smem + 65536);    // [rg][s][32]

    // ---- prologue: q = qw@x + qb for this block's 64 pixels (fp32) ----
    {
        // phase 0: stage qw (8192 floats) into LDS, coalesced
#pragma unroll
        for (int j = 0; j < 4; ++j) {
            const int idx = (j * 512 + tid) * 4;
            *(f32x4*)&qwL[idx] = *(const f32x4*)(qw + idx);
        }
        __syncthreads();

        const int px = tid & 63;
        const int og = tid >> 6;             // c-slice og*32..+32
        const float* ip = x + (size_t)b * NC * NHW + nt * 64 + px;
        const int c0 = og * 32;

        float a[32];
#pragma unroll
        for (int o = 0; o < 32; ++o) a[o] = 0.f;
        for (int cl = 0; cl < 32; cl += 4) {
            const int c = c0 + cl;
            float v0 = ip[(size_t)(c+0)*NHW], v1 = ip[(size_t)(c+1)*NHW];
            float v2 = ip[(size_t)(c+2)*NHW], v3 = ip[(size_t)(c+3)*NHW];
#pragma unroll
            for (int o = 0; o < 32; ++o) {
                f32x4 w = *(const f32x4*)&qwL[o * NC + c];   // LDS broadcast
                a[o] = fmaf(w[0], v0, a[o]); a[o] = fmaf(w[1], v1, a[o]);
                a[o] = fmaf(w[2], v2, a[o]); a[o] = fmaf(w[3], v3, a[o]);
            }
        }
        __syncthreads();                     // all qwL reads done; pl may overwrite
#pragma unroll
        for (int o = 0; o < 32; ++o) pl[(og * 64 + px) * 33 + o] = a[o];
        __syncthreads();

        float s4[4];
#pragma unroll
        for (int j = 0; j < 4; ++j) {
            float sum = 0.f;
#pragma unroll
            for (int gg = 0; gg < 8; ++gg) sum += pl[(gg * 64 + px) * 33 + og * 4 + j];
            s4[j] = sum + qb[og * 4 + j];
        }
        u32x2 pk;
        pk[0] = packbf2(s4[0] * LOG2E, s4[1] * LOG2E);
        pk[1] = packbf2(s4[2] * LOG2E, s4[3] * LOG2E);
        *(u32x2*)&qlds[px][og * 4] = pk;
        __syncthreads();                     // qlds ready; pl dead hereafter
    }

    const unsigned short* ktb = kt + (size_t)b * NHW * NC8;
    const unsigned short* vtb = vt + (size_t)b * (NHW / 8) * NC * 8;

    const int nr0 = nt * 64 + rg * 32;
    const bf16x8 qf0 = *(const bf16x8*)&qlds[rg * 32 + c32][hi * 8];        // d 0..15
    const bf16x8 qf1 = *(const bf16x8*)&qlds[rg * 32 + c32][16 + hi * 8];   // d 16..31

    f32x16 acc[4];
#pragma unroll
    for (int ct = 0; ct < 4; ++ct) acc[ct] = (f32x16)0.0f;
    float lrun = 0.f;
    const f32x16 zz = (f32x16)0.0f;

    int voff[8];
#pragma unroll
    for (int kc = 0; kc < 2; ++kc)
#pragma unroll
        for (int ct = 0; ct < 4; ++ct)
            voff[kc * 4 + ct] = (((kc * 2 + hi) * NC) + cg * 128 + ct * 32 + c32) * 8;

    const size_t VSTEP = (size_t)4 * NC * 8;     // one 32-key step of vt
    const size_t KSTEP = (size_t)32 * NC8;       // one 32-key step of kt

    const unsigned short* vApt = vtb + (size_t)(s * 256) * NC * 8;   // t even
    const unsigned short* vBpt = vApt + VSTEP;                        // t odd
    const unsigned short* kApt = ktb + (size_t)(s * 2048 + c32) * NC8 + hi * 8;
    const unsigned short* kBpt = kApt + KSTEP;

    auto loadV = [&](bf16x8* v, const unsigned short* p) {
#pragma unroll
        for (int i = 0; i < 8; ++i)
            v[i] = *(const bf16x8*)(p + voff[i]);
    };
    auto loadK = [&](bf16x8& ka, bf16x8& kb2, const unsigned short* p) {
        ka  = *(const bf16x8*)p;
        kb2 = *(const bf16x8*)(p + 16);
    };
    auto qkt_pack = [&](const bf16x8& kfa, const bf16x8& kfb, unsigned* w) {
        f32x16 e = __builtin_amdgcn_mfma_f32_32x32x16_bf16(kfa, qf0, zz, 0, 0, 0);
        e = __builtin_amdgcn_mfma_f32_32x32x16_bf16(kfb, qf1, e, 0, 0, 0);
        float ladd = 0.f;
#pragma unroll
        for (int q = 0; q < 8; ++q) {
            const float pa = ex2(e[2 * q]);
            const float pb = ex2(e[2 * q + 1]);
            ladd += pa + pb;
            w[q] = packbf2(pa, pb);
        }
        lrun += ladd;
    };
    auto pv = [&](const bf16x8* v, const unsigned* w) {
#pragma unroll
        for (int kc = 0; kc < 2; ++kc) {
            const unsigned q0 = w[kc * 4 + 0];
            const unsigned q1 = w[kc * 4 + 1];
            const unsigned q2 = w[kc * 4 + 2];
            const unsigned q3 = w[kc * 4 + 3];
            const unsigned q0x = (unsigned)__shfl_xor((int)q0, 32);
            const unsigned q1x = (unsigned)__shfl_xor((int)q1, 32);
            const unsigned q2x = (unsigned)__shfl_xor((int)q2, 32);
            const unsigned q3x = (unsigned)__shfl_xor((int)q3, 32);
            union { unsigned u[4]; bf16x8 vv; } pa;
            pa.u[0] = hi ? q2x : q0;
            pa.u[1] = hi ? q3x : q1;
            pa.u[2] = hi ? q2  : q0x;
            pa.u[3] = hi ? q3  : q1x;
#pragma unroll
            for (int ct = 0; ct < 4; ++ct)
                acc[ct] = __builtin_amdgcn_mfma_f32_32x32x16_bf16(pa.vv, v[kc * 4 + ct], acc[ct], 0, 0, 0);
        }
    };

    // ---- pipeline (r17 order): V/K 2-deep, softmax two ahead ----
    bf16x8 vA[8], vB[8], kAa, kAb, kBa, kBb;
    unsigned wA[8], wB[8];

    loadV(vA, vApt); loadK(kAa, kAb, kApt);
    loadV(vB, vBpt); loadK(kBa, kBb, kBpt);
    qkt_pack(kAa, kAb, wA);                  // w(0)
    kApt += 2 * KSTEP; loadK(kAa, kAb, kApt);        // K(2)
    qkt_pack(kBa, kBb, wB);                  // w(1)
    kBpt += 2 * KSTEP; loadK(kBa, kBb, kBpt);        // K(3)

    for (int tt = 0; tt < 32; ++tt) {
        const int t = tt * 2;
        pv(vA, wA);                          // consume w(t), vA(t)
        if (t + 2 < 64) {
            qkt_pack(kAa, kAb, wA);          // produce w(t+2) from K(t+2)
            vApt += 2 * VSTEP; loadV(vA, vApt);              // V(t+2)
            if (t + 4 < 64) { kApt += 2 * KSTEP; loadK(kAa, kAb, kApt); }  // K(t+4)
        }
        pv(vB, wB);                          // consume w(t+1), vB(t+1)
        if (t + 3 < 64) {
            qkt_pack(kBa, kBb, wB);          // produce w(t+3) from K(t+3)
            vBpt += 2 * VSTEP; loadV(vB, vBpt);              // V(t+3)
            if (t + 5 < 64) { kBpt += 2 * KSTEP; loadK(kBa, kBb, kBpt); }  // K(t+5)
        }
    }

    // ---- 2-way s-combine ----
    lrun += __shfl_xor(lrun, 32);
    __syncthreads();                          // all waves past prologue-pl use
    ml[(rg * 2 + s) * 32 + c32] = lrun;
    __syncthreads();
    const float L = ml[(rg * 2 + 0) * 32 + c32] + ml[(rg * 2 + 1) * 32 + c32];
    const float gil = gamma[0] / L;
    float il[16];
#pragma unroll
    for (int r = 0; r < 16; ++r)
        il[r] = __shfl(gil, (r & 3) + 8 * (r >> 2) + 4 * hi);

    if (s == 1) {
#pragma unroll
        for (int ct = 0; ct < 4; ++ct)
#pragma unroll
            for (int rq = 0; rq < 4; ++rq) {
                f32x4 v;
#pragma unroll
                for (int j = 0; j < 4; ++j) v[j] = acc[ct][rq * 4 + j];
                *(f32x4*)(obuf + ((((rg * 2 + cg) * 16 + ct * 4 + rq) * 64) + lane) * 4) = v;
            }
    }
    __syncthreads();
    if (s == 0) {
#pragma unroll
        for (int ct = 0; ct < 4; ++ct) {
            const int c = cg * 128 + ct * 32 + c32;
#pragma unroll
            for (int rq = 0; rq < 4; ++rq) {
                const f32x4 p = *(const f32x4*)(obuf + ((((rg * 2 + cg) * 16 + ct * 4 + rq) * 64) + lane) * 4);
                const int nglob = nt * 64 + rg * 32 + rq * 8 + hi * 4;
                const size_t o = ((size_t)b * NC + c) * NHW + nglob;
                const f32x4 xv = *(const f32x4*)(x + o);
                f32x4 res;
#pragma unroll
                for (int j = 0; j < 4; ++j) {
                    const float v = acc[ct][rq * 4 + j] + p[j];
                    res[j] = fmaf(v, il[rq * 4 + j], xv[j]);
                }
                *(f32x4*)(out + o) = res;
            }
        }
    }
}

extern "C" void kernel_launch(void* const* d_in, const int* in_sizes, int n_in,
                              void* d_out, int out_size, void* d_ws, size_t ws_size,
                              hipStream_t stream) {
    const float* x     = (const float*)d_in[0];
    const float* g     = (const float*)d_in[1];
    const float* qw    = (const float*)d_in[2];
    const float* qb    = (const float*)d_in[3];
    const float* kw    = (const float*)d_in[4];
    const float* kb    = (const float*)d_in[5];
    const float* vw    = (const float*)d_in[6];
    const float* vb    = (const float*)d_in[7];
    const float* gamma = (const float*)d_in[8];
    float* out = (float*)d_out;

    unsigned short* kt = (unsigned short*)d_ws;
    unsigned short* vt = kt + (size_t)NB * NHW * NC8;

    v_proj<<<512, 256, 0, stream>>>(g, vw, vb, kw, kb, vt, kt);
    attn  <<<NB * (NHW / 64), 512, 0, stream>>>(x, qw, qb, kt, vt, gamma, out);
}